// Round 1
// baseline (243.264 us; speedup 1.0000x reference)
//
#include <hip/hip_runtime.h>
#include <hip/hip_bf16.h>
#include <stdint.h>

// NearestUpsampling (x2) + 3x3 VALID conv == per-parity 2x2 conv on original x
// == implicit GEMM M=16*63*63=63504, N=(4 par)*(128 Cout), K=128c*4taps=512.
// R5: occupancy play. BM 64->32 halves LDS (33.3 KB -> 4 blocks fit) and
//     halves acc (32 regs). __launch_bounds__(512,6) caps regs at 85 so
//     3 blocks (24 waves/CU, 75%) are resident instead of ~1.5 (37.6%).
//     K-loop / weight layout / epilogue unchanged from verified R4.

#define B_    16
#define CIN   128
#define HIN   64
#define WIN   64
#define COUT  128
#define HO    126
#define WO    126
#define M_TOT (B_ * 63 * 63)   // 63504
#define BM    32
#define KTILES 16
#define AS_K  520              // bf16 row stride: 1040 B (16B-aligned, bank-spread)

typedef __bf16 bf16;
typedef __bf16 bf16x4 __attribute__((ext_vector_type(4)));
typedef __bf16 bf16x8 __attribute__((ext_vector_type(8)));
typedef float  floatx4 __attribute__((ext_vector_type(4)));

// ---------------------------------------------------------------------------
// Prep: combine 3x3 weights into parity 2x2 weights (bf16).
// Layout: wb[(((kt*4 + par)*128 + o)*32 + k32)], k = kt*32+k32 = c*4 + u*2 + v.
// A wave's (par,o,quad) MFMA fragment is a contiguous 16B run of this array.
// ---------------------------------------------------------------------------
__global__ void prep_weights(const float* __restrict__ w, bf16* __restrict__ wb) {
    int idx = blockIdx.x * 256 + threadIdx.x;
    if (idx >= 4 * KTILES * COUT * 32) return;   // 262144
    int k32 = idx & 31;
    int o   = (idx >> 5) & 127;
    int par = (idx >> 12) & 3;
    int kt  = idx >> 14;
    int k = kt * 32 + k32;
    int c = k >> 2, u = (k >> 1) & 1, v = k & 1;
    int a = par >> 1, bp = par & 1;
    int dy0, dy1, ndy, dx0, dx1, ndx;
    if (u == 0) { if (a == 0) { dy0 = 0; dy1 = 1; ndy = 2; } else { dy0 = 0; dy1 = 0; ndy = 1; } }
    else        { if (a == 0) { dy0 = 2; dy1 = 2; ndy = 1; } else { dy0 = 1; dy1 = 2; ndy = 2; } }
    if (v == 0) { if (bp == 0) { dx0 = 0; dx1 = 1; ndx = 2; } else { dx0 = 0; dx1 = 0; ndx = 1; } }
    else        { if (bp == 0) { dx0 = 2; dx1 = 2; ndx = 1; } else { dx0 = 1; dx1 = 2; ndx = 2; } }
    const float* wp = w + (o * CIN + c) * 9;
    float s = wp[dy0 * 3 + dx0];
    if (ndx == 2) s += wp[dy0 * 3 + dx1];
    if (ndy == 2) { s += wp[dy1 * 3 + dx0]; if (ndx == 2) s += wp[dy1 * 3 + dx1]; }
    wb[idx] = (bf16)s;
}

// ---------------------------------------------------------------------------
// Main kernel. 512 threads = 8 waves: a = wid>>2 (row parity), oq = wid&3
// (o-quarter). Wave: 32 o x 32 m x both bp via mfma(wf, af) -> D[row=o][col=m].
// ---------------------------------------------------------------------------
__global__ __launch_bounds__(512, 6)
void upconv_gemm(const float* __restrict__ x, const bf16* __restrict__ wb,
                 const float* __restrict__ bias, float* __restrict__ out) {
    __shared__ bf16 As[BM * AS_K];   // 33280 B: [m_local][k], whole K

    const int t    = threadIdx.x;
    const int lane = t & 63;
    const int wid  = t >> 6;
    const int a    = wid >> 2;          // output-row parity
    const int oq   = wid & 3;           // o-quarter
    const int quad = lane >> 4;
    const int l15  = lane & 15;
    const int kq   = quad * 8;

    const int m0 = blockIdx.x * BM;

    // --- stage the ENTIRE A tile (all 512 k) once ---
    // 512 threads / 32 rows: each row staged by 16 threads, 8 channels each.
    const int ml = t & 31;              // m-row handled by this thread
    const int cg = t >> 5;              // channel group 0..15
    const int m_mine = m0 + ml;
    const bool mvalid = (m_mine < M_TOT);
    int b_ = 0, p_ = 0, q_ = 0;
    if (mvalid) { b_ = m_mine / 3969; int rr = m_mine - b_ * 3969; p_ = rr / 63; q_ = rr - p_ * 63; }
    const float* xbase = x + ((size_t)(b_ * CIN) * HIN + p_) * WIN + q_;

    #pragma unroll
    for (int cc = 0; cc < 8; ++cc) {
        const int c = cg * 8 + cc;      // channel
        float f00 = 0.f, f01 = 0.f, f10 = 0.f, f11 = 0.f;
        if (mvalid) {
            const float* pa = xbase + (size_t)c * (HIN * WIN);
            f00 = pa[0]; f01 = pa[1]; f10 = pa[WIN]; f11 = pa[WIN + 1];
        }
        bf16x4 v; v[0] = (bf16)f00; v[1] = (bf16)f01; v[2] = (bf16)f10; v[3] = (bf16)f11;
        *(bf16x4*)&As[ml * AS_K + c * 4] = v;   // k = c*4 + tap
    }
    __syncthreads();   // the ONLY barrier

    // --- K-loop: no barriers, wf straight from global (L2-resident) ---
    const bf16* wwave = wb + ((size_t)(a * 2) * COUT + oq * 32 + l15) * 32 + kq;

    floatx4 acc[2][2][2] = {};   // [bp][mt][nt]

    #pragma unroll
    for (int kt = 0; kt < KTILES; ++kt) {
        bf16x8 af[2], wf[2][2];
        #pragma unroll
        for (int i = 0; i < 2; ++i)
            af[i] = *(const bf16x8*)&As[(i * 16 + l15) * AS_K + kt * 32 + kq];
        #pragma unroll
        for (int bp = 0; bp < 2; ++bp)
            #pragma unroll
            for (int nt = 0; nt < 2; ++nt)
                wf[bp][nt] = *(const bf16x8*)(wwave
                    + ((size_t)kt * 4 * COUT + (size_t)bp * COUT + nt * 16) * 32);
        #pragma unroll
        for (int bp = 0; bp < 2; ++bp)
            #pragma unroll
            for (int mt = 0; mt < 2; ++mt)
                #pragma unroll
                for (int nt = 0; nt < 2; ++nt)
                    acc[bp][mt][nt] = __builtin_amdgcn_mfma_f32_16x16x32_bf16(
                        wf[bp][nt], af[mt], acc[bp][mt][nt], 0, 0, 0);
    }

    // ---- epilogue: direct coalesced float2 stores (no LDS) ----
    // D layout: col = lane&15 -> m, row = quad*4+ri -> o (within 16-tile).
    float bv[2][4];
    #pragma unroll
    for (int nt = 0; nt < 2; ++nt)
        #pragma unroll
        for (int ri = 0; ri < 4; ++ri)
            bv[nt][ri] = bias[oq * 32 + nt * 16 + quad * 4 + ri];

    #pragma unroll
    for (int mt = 0; mt < 2; ++mt) {
        const int m = m0 + mt * 16 + l15;
        const bool v = (m < M_TOT);
        int b = 0, p = 0, q = 0;
        if (v) { b = m / 3969; int rr = m - b * 3969; p = rr / 63; q = rr - p * 63; }
        float* base = out + (size_t)b * (COUT * HO * WO) + (size_t)(2 * p + a) * WO + 2 * q;
        #pragma unroll
        for (int nt = 0; nt < 2; ++nt) {
            #pragma unroll
            for (int ri = 0; ri < 4; ++ri) {
                const int o = oq * 32 + nt * 16 + quad * 4 + ri;
                if (v) {
                    float2 r = make_float2(acc[0][mt][nt][ri] + bv[nt][ri],
                                           acc[1][mt][nt][ri] + bv[nt][ri]);
                    *(float2*)(base + (size_t)o * (HO * WO)) = r;
                }
            }
        }
    }
}

extern "C" void kernel_launch(void* const* d_in, const int* in_sizes, int n_in,
                              void* d_out, int out_size, void* d_ws, size_t ws_size,
                              hipStream_t stream) {
    const float* x    = (const float*)d_in[0];
    const float* w    = (const float*)d_in[1];
    const float* bias = (const float*)d_in[2];
    float* out = (float*)d_out;
    bf16* wb = (bf16*)d_ws;   // 512 KB

    prep_weights<<<(4 * KTILES * COUT * 32 + 255) / 256, 256, 0, stream>>>(w, wb);

    dim3 grid((M_TOT + BM - 1) / BM);   // 1985 blocks
    upconv_gemm<<<grid, 512, 0, stream>>>(x, wb, bias, out);
}

// Round 2
// 233.333 us; speedup vs baseline: 1.0426x; 1.0426x over previous
//
#include <hip/hip_runtime.h>
#include <hip/hip_bf16.h>
#include <stdint.h>

// NearestUpsampling (x2) + 3x3 VALID conv == per-parity 2x2 conv on original x
// == implicit GEMM M=16*63*63=63504, N=(4 par)*(128 Cout), K=128c*4taps=512.
// R6: back to R4 geometry (BM=64). The R4 loop was latency-bound: 128-reg cap
//     (64 arch + 64 acc) left ZERO room to prefetch the per-kt weight loads
//     (L2 ~200cyc exposed every kt -> MfmaUtil 13%). Now __launch_bounds__(512,2)
//     (256-reg cap, 1 block/CU) + explicit A/B double-buffer software pipeline
//     for wf (global/L2) and af (LDS), kt=0/1 wf issued before staging so L2
//     latency hides under the x HBM loads. s_setprio around MFMA clusters
//     (independent-wave regime).

#define B_    16
#define CIN   128
#define HIN   64
#define WIN   64
#define COUT  128
#define HO    126
#define WO    126
#define M_TOT (B_ * 63 * 63)   // 63504
#define BM    64
#define KTILES 16
#define AS_K  520              // bf16 row stride: 1040 B (16B-aligned, bank-spread)

typedef __bf16 bf16;
typedef __bf16 bf16x4 __attribute__((ext_vector_type(4)));
typedef __bf16 bf16x8 __attribute__((ext_vector_type(8)));
typedef float  floatx4 __attribute__((ext_vector_type(4)));

// ---------------------------------------------------------------------------
// Prep: combine 3x3 weights into parity 2x2 weights (bf16).
// Layout: wb[(((kt*4 + par)*128 + o)*32 + k32)], k = kt*32+k32 = c*4 + u*2 + v.
// A wave's (par,o,quad) MFMA fragment is a contiguous 16B run of this array.
// ---------------------------------------------------------------------------
__global__ void prep_weights(const float* __restrict__ w, bf16* __restrict__ wb) {
    int idx = blockIdx.x * 256 + threadIdx.x;
    if (idx >= 4 * KTILES * COUT * 32) return;   // 262144
    int k32 = idx & 31;
    int o   = (idx >> 5) & 127;
    int par = (idx >> 12) & 3;
    int kt  = idx >> 14;
    int k = kt * 32 + k32;
    int c = k >> 2, u = (k >> 1) & 1, v = k & 1;
    int a = par >> 1, bp = par & 1;
    int dy0, dy1, ndy, dx0, dx1, ndx;
    if (u == 0) { if (a == 0) { dy0 = 0; dy1 = 1; ndy = 2; } else { dy0 = 0; dy1 = 0; ndy = 1; } }
    else        { if (a == 0) { dy0 = 2; dy1 = 2; ndy = 1; } else { dy0 = 1; dy1 = 2; ndy = 2; } }
    if (v == 0) { if (bp == 0) { dx0 = 0; dx1 = 1; ndx = 2; } else { dx0 = 0; dx1 = 0; ndx = 1; } }
    else        { if (bp == 0) { dx0 = 2; dx1 = 2; ndx = 1; } else { dx0 = 1; dx1 = 2; ndx = 2; } }
    const float* wp = w + (o * CIN + c) * 9;
    float s = wp[dy0 * 3 + dx0];
    if (ndx == 2) s += wp[dy0 * 3 + dx1];
    if (ndy == 2) { s += wp[dy1 * 3 + dx0]; if (ndx == 2) s += wp[dy1 * 3 + dx1]; }
    wb[idx] = (bf16)s;
}

// ---------------------------------------------------------------------------
// Main kernel. 512 threads = 8 waves: a = wid>>2 (row parity), oq = wid&3
// (o-quarter). Wave: 32 o x 64 m x both bp via mfma(wf, af) -> D[row=o][col=m].
// ---------------------------------------------------------------------------
__global__ __launch_bounds__(512, 2)
void upconv_gemm(const float* __restrict__ x, const bf16* __restrict__ wb,
                 const float* __restrict__ bias, float* __restrict__ out) {
    __shared__ bf16 As[BM * AS_K];   // 66560 B: [m_local][k], whole K

    const int t    = threadIdx.x;
    const int lane = t & 63;
    const int wid  = t >> 6;
    const int a    = wid >> 2;          // output-row parity
    const int oq   = wid & 3;           // o-quarter
    const int quad = lane >> 4;
    const int l15  = lane & 15;
    const int kq   = quad * 8;

    const int m0 = blockIdx.x * BM;

    const bf16* wwave = wb + ((size_t)(a * 2) * COUT + oq * 32 + l15) * 32 + kq;

    // --- issue wf prefetch for kt=0,1 BEFORE staging: L2 latency hides under
    //     the x HBM loads of the staging phase ---
    bf16x8 wfA[2][2], wfB[2][2];
    #pragma unroll
    for (int bp = 0; bp < 2; ++bp)
        #pragma unroll
        for (int nt = 0; nt < 2; ++nt) {
            wfA[bp][nt] = *(const bf16x8*)(wwave
                + ((size_t)0 * 4 * COUT + (size_t)bp * COUT + nt * 16) * 32);
            wfB[bp][nt] = *(const bf16x8*)(wwave
                + ((size_t)1 * 4 * COUT + (size_t)bp * COUT + nt * 16) * 32);
        }

    // --- stage the ENTIRE A tile (all 512 k) once ---
    const int ml = lane;                // m-row handled by this thread
    const int m_mine = m0 + ml;
    const bool mvalid = (m_mine < M_TOT);
    int b_ = 0, p_ = 0, q_ = 0;
    if (mvalid) { b_ = m_mine / 3969; int rr = m_mine - b_ * 3969; p_ = rr / 63; q_ = rr - p_ * 63; }
    const float* xbase = x + ((size_t)(b_ * CIN) * HIN + p_) * WIN + q_;

    #pragma unroll
    for (int cc = 0; cc < 16; ++cc) {
        const int c = wid * 16 + cc;    // channel: wave covers 16 channels
        float f00 = 0.f, f01 = 0.f, f10 = 0.f, f11 = 0.f;
        if (mvalid) {
            const float* pa = xbase + (size_t)c * (HIN * WIN);
            f00 = pa[0]; f01 = pa[1]; f10 = pa[WIN]; f11 = pa[WIN + 1];
        }
        bf16x4 v; v[0] = (bf16)f00; v[1] = (bf16)f01; v[2] = (bf16)f10; v[3] = (bf16)f11;
        *(bf16x4*)&As[ml * AS_K + c * 4] = v;   // k = c*4 + tap
    }
    __syncthreads();   // the ONLY barrier

    // --- af preload for kt=0,1 ---
    bf16x8 afA[4], afB[4];
    #pragma unroll
    for (int i = 0; i < 4; ++i) {
        afA[i] = *(const bf16x8*)&As[(i * 16 + l15) * AS_K + 0 * 32 + kq];
        afB[i] = *(const bf16x8*)&As[(i * 16 + l15) * AS_K + 1 * 32 + kq];
    }

    floatx4 acc[2][4][2] = {};   // [bp][mt][nt]

    // --- K-loop: A/B software pipeline, no barriers, all indices static ---
    #pragma unroll
    for (int kt2 = 0; kt2 < KTILES; kt2 += 2) {
        // compute kt2 from A
        __builtin_amdgcn_s_setprio(1);
        #pragma unroll
        for (int bp = 0; bp < 2; ++bp)
            #pragma unroll
            for (int mt = 0; mt < 4; ++mt)
                #pragma unroll
                for (int nt = 0; nt < 2; ++nt)
                    acc[bp][mt][nt] = __builtin_amdgcn_mfma_f32_16x16x32_bf16(
                        wfA[bp][nt], afA[mt], acc[bp][mt][nt], 0, 0, 0);
        __builtin_amdgcn_s_setprio(0);

        // reload A <- kt2+2
        if (kt2 + 2 < KTILES) {
            const int ktn = kt2 + 2;
            #pragma unroll
            for (int i = 0; i < 4; ++i)
                afA[i] = *(const bf16x8*)&As[(i * 16 + l15) * AS_K + ktn * 32 + kq];
            #pragma unroll
            for (int bp = 0; bp < 2; ++bp)
                #pragma unroll
                for (int nt = 0; nt < 2; ++nt)
                    wfA[bp][nt] = *(const bf16x8*)(wwave
                        + ((size_t)ktn * 4 * COUT + (size_t)bp * COUT + nt * 16) * 32);
        }

        // compute kt2+1 from B
        __builtin_amdgcn_s_setprio(1);
        #pragma unroll
        for (int bp = 0; bp < 2; ++bp)
            #pragma unroll
            for (int mt = 0; mt < 4; ++mt)
                #pragma unroll
                for (int nt = 0; nt < 2; ++nt)
                    acc[bp][mt][nt] = __builtin_amdgcn_mfma_f32_16x16x32_bf16(
                        wfB[bp][nt], afB[mt], acc[bp][mt][nt], 0, 0, 0);
        __builtin_amdgcn_s_setprio(0);

        // reload B <- kt2+3
        if (kt2 + 3 < KTILES) {
            const int ktn = kt2 + 3;
            #pragma unroll
            for (int i = 0; i < 4; ++i)
                afB[i] = *(const bf16x8*)&As[(i * 16 + l15) * AS_K + ktn * 32 + kq];
            #pragma unroll
            for (int bp = 0; bp < 2; ++bp)
                #pragma unroll
                for (int nt = 0; nt < 2; ++nt)
                    wfB[bp][nt] = *(const bf16x8*)(wwave
                        + ((size_t)ktn * 4 * COUT + (size_t)bp * COUT + nt * 16) * 32);
        }
    }

    // ---- epilogue: direct coalesced float2 stores (no LDS) ----
    // D layout: col = lane&15 -> m, row = quad*4+ri -> o (within 16-tile).
    float bv[2][4];
    #pragma unroll
    for (int nt = 0; nt < 2; ++nt)
        #pragma unroll
        for (int ri = 0; ri < 4; ++ri)
            bv[nt][ri] = bias[oq * 32 + nt * 16 + quad * 4 + ri];

    #pragma unroll
    for (int mt = 0; mt < 4; ++mt) {
        const int m = m0 + mt * 16 + l15;
        const bool v = (m < M_TOT);
        int b = 0, p = 0, q = 0;
        if (v) { b = m / 3969; int rr = m - b * 3969; p = rr / 63; q = rr - p * 63; }
        float* base = out + (size_t)b * (COUT * HO * WO) + (size_t)(2 * p + a) * WO + 2 * q;
        #pragma unroll
        for (int nt = 0; nt < 2; ++nt) {
            #pragma unroll
            for (int ri = 0; ri < 4; ++ri) {
                const int o = oq * 32 + nt * 16 + quad * 4 + ri;
                if (v) {
                    float2 r = make_float2(acc[0][mt][nt][ri] + bv[nt][ri],
                                           acc[1][mt][nt][ri] + bv[nt][ri]);
                    *(float2*)(base + (size_t)o * (HO * WO)) = r;
                }
            }
        }
    }
}

extern "C" void kernel_launch(void* const* d_in, const int* in_sizes, int n_in,
                              void* d_out, int out_size, void* d_ws, size_t ws_size,
                              hipStream_t stream) {
    const float* x    = (const float*)d_in[0];
    const float* w    = (const float*)d_in[1];
    const float* bias = (const float*)d_in[2];
    float* out = (float*)d_out;
    bf16* wb = (bf16*)d_ws;   // 512 KB

    prep_weights<<<(4 * KTILES * COUT * 32 + 255) / 256, 256, 0, stream>>>(w, wb);

    dim3 grid((M_TOT + BM - 1) / BM);   // 993 blocks
    upconv_gemm<<<grid, 512, 0, stream>>>(x, wb, bias, out);
}